// Round 1
// baseline (2635.574 us; speedup 1.0000x reference)
//
#include <hip/hip_runtime.h>
#include <math.h>

#define N 4096
#define NREL 5
#define NCH 2
#define NEDGE 131072
#define THRESH 0.05f
#define FSCALE 268435456.0f          // 2^28
#define INV_FSCALE (1.0f/268435456.0f)

// ws layout (elements of 4 bytes):
//   [0,            2*N*N)  : A1  (int32 fixed-point during scatter, fp32 after convert)
//   [2*N*N,        4*N*N)  : A2  (same)
//   [4*N*N, 4*N*N + 20)    : F1 (10), F2 (10) as fp32
#define A1_OFF ((size_t)0)
#define A2_OFF ((size_t)2 * N * N)
#define F_OFF  ((size_t)4 * N * N)

__global__ void softmax_kernel(const float* __restrict__ w1,
                               const float* __restrict__ w2,
                               float* __restrict__ F,
                               float* __restrict__ out_tail) {
    int c = threadIdx.x;            // 0,1 -> w1 rows; 2,3 -> w2 rows
    if (c < 2 * NCH) {
        const float* w = (c < NCH) ? w1 : w2;
        int row = c % NCH;
        int base = (c < NCH) ? 0 : NCH * NREL;
        float m = -1e30f;
        for (int r = 0; r < NREL; ++r) m = fmaxf(m, w[row * NREL + r]);
        float e[NREL];
        float s = 0.f;
        for (int r = 0; r < NREL; ++r) { e[r] = expf(w[row * NREL + r] - m); s += e[r]; }
        float inv = 1.0f / s;
        for (int r = 0; r < NREL; ++r) {
            float f = e[r] * inv;
            F[base + row * NREL + r] = f;
            out_tail[base + row * NREL + r] = f;
        }
    }
}

__global__ void scatter_kernel(const int* __restrict__ ei,
                               const float* __restrict__ ev,
                               const float* __restrict__ F,
                               int* __restrict__ A1,
                               int* __restrict__ A2) {
    int t = blockIdx.x * blockDim.x + threadIdx.x;
    if (t >= NREL * NEDGE) return;
    int r = t / NEDGE;
    int e = t - r * NEDGE;
    int i = ei[(size_t)(r * 2 + 0) * NEDGE + e];
    int j = ei[(size_t)(r * 2 + 1) * NEDGE + e];
    float v = ev[(size_t)r * NEDGE + e];
    size_t cell = (size_t)i * N + j;
#pragma unroll
    for (int c = 0; c < NCH; ++c) {
        float f1 = F[c * NREL + r];
        float f2 = F[NCH * NREL + c * NREL + r];
        int q1 = __float2int_rn(f1 * v * FSCALE);
        int q2 = __float2int_rn(f2 * v * FSCALE);
        atomicAdd(&A1[(size_t)c * N * N + cell], q1);
        atomicAdd(&A2[(size_t)c * N * N + cell], q2);
    }
}

__global__ void convert_kernel(int* __restrict__ buf, long long n) {
    long long idx = (long long)blockIdx.x * blockDim.x + threadIdx.x;
    long long stride = (long long)gridDim.x * blockDim.x;
    for (; idx < n; idx += stride) {
        float f = (float)buf[idx] * INV_FSCALE;
        buf[idx] = __float_as_int(f);
    }
}

#define BM 128
#define BN 128
#define BK 16

__launch_bounds__(256)
__global__ void gemm_kernel(const float* __restrict__ A1,
                            const float* __restrict__ A2,
                            float* __restrict__ out) {
    __shared__ float As[BK][BM];   // A tile stored transposed: As[k][m]
    __shared__ float Bs[BK][BN];   // Bs[k][n]

    const int c  = blockIdx.z;
    const int m0 = blockIdx.y * BM;
    const int n0 = blockIdx.x * BN;
    const float* __restrict__ A = A1 + (size_t)c * N * N;
    const float* __restrict__ B = A2 + (size_t)c * N * N;

    const int tid = threadIdx.x;
    const int tx = tid % 16;        // output col group
    const int ty = tid / 16;        // output row group

    float acc[8][8];
#pragma unroll
    for (int i = 0; i < 8; ++i)
#pragma unroll
        for (int j = 0; j < 8; ++j) acc[i][j] = 0.f;

    for (int k0 = 0; k0 < N; k0 += BK) {
        // Load A tile: 128 rows x 16 k, 512 float4, 2 per thread (transposed store)
#pragma unroll
        for (int l = 0; l < 2; ++l) {
            int idx = tid * 2 + l;           // 0..511
            int row = idx >> 2;              // 0..127
            int kk4 = (idx & 3) * 4;         // 0,4,8,12
            float4 v = *(const float4*)&A[(size_t)(m0 + row) * N + k0 + kk4];
            As[kk4 + 0][row] = v.x;
            As[kk4 + 1][row] = v.y;
            As[kk4 + 2][row] = v.z;
            As[kk4 + 3][row] = v.w;
        }
        // Load B tile: 16 k x 128 cols, 512 float4, 2 per thread
#pragma unroll
        for (int l = 0; l < 2; ++l) {
            int idx = tid * 2 + l;
            int row = idx >> 5;              // k 0..15
            int j4 = (idx & 31) * 4;         // 0..124
            *(float4*)&Bs[row][j4] = *(const float4*)&B[(size_t)(k0 + row) * N + n0 + j4];
        }
        __syncthreads();

#pragma unroll
        for (int kk = 0; kk < BK; ++kk) {
            float a[8], b[8];
            *(float4*)&a[0] = *(const float4*)&As[kk][ty * 8];
            *(float4*)&a[4] = *(const float4*)&As[kk][ty * 8 + 4];
            *(float4*)&b[0] = *(const float4*)&Bs[kk][tx * 8];
            *(float4*)&b[4] = *(const float4*)&Bs[kk][tx * 8 + 4];
#pragma unroll
            for (int i = 0; i < 8; ++i)
#pragma unroll
                for (int j = 0; j < 8; ++j)
                    acc[i][j] = fmaf(a[i], b[j], acc[i][j]);
        }
        __syncthreads();
    }

    // Epilogue: threshold and store
    size_t base = (size_t)c * N * N;
#pragma unroll
    for (int i = 0; i < 8; ++i) {
        int m = m0 + ty * 8 + i;
#pragma unroll
        for (int j4 = 0; j4 < 2; ++j4) {
            float4 v;
            float x0 = acc[i][j4 * 4 + 0];
            float x1 = acc[i][j4 * 4 + 1];
            float x2 = acc[i][j4 * 4 + 2];
            float x3 = acc[i][j4 * 4 + 3];
            v.x = (x0 > THRESH) ? x0 : 0.f;
            v.y = (x1 > THRESH) ? x1 : 0.f;
            v.z = (x2 > THRESH) ? x2 : 0.f;
            v.w = (x3 > THRESH) ? x3 : 0.f;
            *(float4*)&out[base + (size_t)m * N + n0 + tx * 8 + j4 * 4] = v;
        }
    }
}

extern "C" void kernel_launch(void* const* d_in, const int* in_sizes, int n_in,
                              void* d_out, int out_size, void* d_ws, size_t ws_size,
                              hipStream_t stream) {
    const int*   ei = (const int*)d_in[0];     // [5, 2, 131072]
    const float* ev = (const float*)d_in[1];   // [5, 131072]
    const float* w1 = (const float*)d_in[2];   // [2, 5]
    const float* w2 = (const float*)d_in[3];   // [2, 5]
    float* out = (float*)d_out;                // H (2*N*N) then F1(10), F2(10)

    int*   A1i = (int*)d_ws + A1_OFF;
    int*   A2i = (int*)d_ws + A2_OFF;
    float* F   = (float*)d_ws + F_OFF;

    // Zero fixed-point accumulators (ws is poisoned by harness; must re-zero per launch)
    hipMemsetAsync(d_ws, 0, (size_t)4 * N * N * sizeof(int), stream);

    float* out_tail = out + (size_t)NCH * N * N;
    softmax_kernel<<<1, 64, 0, stream>>>(w1, w2, F, out_tail);

    int total_edges = NREL * NEDGE;
    scatter_kernel<<<(total_edges + 255) / 256, 256, 0, stream>>>(ei, ev, F, A1i, A2i);

    long long conv_n = (long long)4 * N * N;
    convert_kernel<<<2048, 256, 0, stream>>>((int*)d_ws, conv_n);

    dim3 grid(N / BN, N / BM, NCH);
    gemm_kernel<<<grid, 256, 0, stream>>>((const float*)d_ws + A1_OFF,
                                          (const float*)d_ws + A2_OFF,
                                          out);
}

// Round 3
// 565.097 us; speedup vs baseline: 4.6639x; 4.6639x over previous
//
#include <hip/hip_runtime.h>
#include <math.h>

#define N 4096
#define NREL 5
#define NCH 2
#define NEDGE 131072
#define THRESH 0.05f
#define FSCALE 268435456.0f          // 2^28 fixed point for adjacency entries
#define INV_P56 (1.0/72057594037927936.0)   // 2^-56 (double, exact)
#define CAP 512                      // CSR row capacity (row nnz ~160 +- 13, max ~220)
#define KCAP 512

// ws layout in 4-byte elements (regions reused across the channel loop):
//   A1d  [0,        N*N)        dense A1 channel c, int32 fixed-point (2^-28)
//   A2d  [N*N,      2*N*N)      dense A2 channel c, int32 fixed-point
//   CNT  [2*N*N,    2*N*N+N)    CSR row nnz counts
//   CSR  [2*N*N+N,  +2*N*CAP)   int2 entries (col, raw int32 fixed-point value)
//   F    after CSR              softmax weights, 20 floats
#define A1_OFF  ((size_t)0)
#define A2_OFF  ((size_t)N * N)
#define CNT_OFF ((size_t)2 * N * N)
#define CSR_OFF ((size_t)2 * N * N + N)
#define F_OFF   (CSR_OFF + (size_t)2 * N * CAP)

__global__ void softmax_kernel(const float* __restrict__ w1,
                               const float* __restrict__ w2,
                               float* __restrict__ F,
                               float* __restrict__ out_tail) {
    int c = threadIdx.x;
    if (c < 2 * NCH) {
        const float* w = (c < NCH) ? w1 : w2;
        int row = c % NCH;
        int base = (c < NCH) ? 0 : NCH * NREL;
        float m = -1e30f;
        for (int r = 0; r < NREL; ++r) m = fmaxf(m, w[row * NREL + r]);
        float e[NREL];
        float s = 0.f;
        for (int r = 0; r < NREL; ++r) { e[r] = expf(w[row * NREL + r] - m); s += e[r]; }
        float inv = 1.0f / s;
        for (int r = 0; r < NREL; ++r) {
            float f = e[r] * inv;
            F[base + row * NREL + r] = f;
            out_tail[base + row * NREL + r] = f;
        }
    }
}

__global__ void scatter_ch(const int* __restrict__ ei,
                           const float* __restrict__ ev,
                           const float* __restrict__ F,
                           int* __restrict__ A1d,
                           int* __restrict__ A2d,
                           int c) {
    int t = blockIdx.x * blockDim.x + threadIdx.x;
    if (t >= NREL * NEDGE) return;
    int r = t / NEDGE;
    int e = t - r * NEDGE;
    int i = ei[(size_t)(r * 2 + 0) * NEDGE + e];
    int j = ei[(size_t)(r * 2 + 1) * NEDGE + e];
    float v = ev[(size_t)r * NEDGE + e];
    size_t cell = (size_t)i * N + j;
    float f1 = F[c * NREL + r];
    float f2 = F[NCH * NREL + c * NREL + r];
    // per-edge quantization identical to the round-1 passing kernel
    atomicAdd(&A1d[cell], __float2int_rn(f1 * v * FSCALE));
    atomicAdd(&A2d[cell], __float2int_rn(f2 * v * FSCALE));
}

__launch_bounds__(256)
__global__ void csr_build(const int* __restrict__ A2d,
                          int* __restrict__ CNT,
                          int2* __restrict__ CSR) {
    __shared__ int cnt;
    int k = blockIdx.x;
    if (threadIdx.x == 0) cnt = 0;
    __syncthreads();
    const int4* row4 = (const int4*)(A2d + (size_t)k * N);
    for (int t = threadIdx.x; t < N / 4; t += 256) {
        int4 a = row4[t];
        int col = t * 4;
        int vals[4] = {a.x, a.y, a.z, a.w};
#pragma unroll
        for (int u = 0; u < 4; ++u) {
            if (vals[u] != 0) {
                int pos = atomicAdd(&cnt, 1);
                if (pos < CAP)
                    CSR[(size_t)k * CAP + pos] = make_int2(col + u, vals[u]);
            }
        }
    }
    __syncthreads();
    if (threadIdx.x == 0) CNT[k] = min(cnt, CAP);
}

__launch_bounds__(256)
__global__ void spgemm(const int* __restrict__ A1d,
                       const int* __restrict__ CNT,
                       const int2* __restrict__ CSR,
                       float* __restrict__ out,
                       int c) {
    __shared__ unsigned long long acc[N];   // 32 KB exact int64 row accumulator
    __shared__ int2 klist[KCAP];            // nonzeros of A1 row m: (k, raw int value)
    __shared__ int kcnt;
    int m = blockIdx.x;
    for (int i = threadIdx.x; i < N; i += 256) acc[i] = 0ULL;
    if (threadIdx.x == 0) kcnt = 0;
    __syncthreads();

    // compact nonzeros of dense A1 row m into klist (raw ints, no conversion)
    const int4* row4 = (const int4*)(A1d + (size_t)m * N);
    for (int t = threadIdx.x; t < N / 4; t += 256) {
        int4 a = row4[t];
        int col = t * 4;
        int vals[4] = {a.x, a.y, a.z, a.w};
#pragma unroll
        for (int u = 0; u < 4; ++u) {
            if (vals[u] != 0) {
                int pos = atomicAdd(&kcnt, 1);
                if (pos < KCAP)
                    klist[pos] = make_int2(col + u, vals[u]);
            }
        }
    }
    __syncthreads();

    int nk = min(kcnt, KCAP);
    int wave = threadIdx.x >> 6;
    int lane = threadIdx.x & 63;
    // each wave takes k's [wave::4]; lanes stride the CSR row entries.
    // product ia*iv < 2^62 fits int64 exactly; integer adds are order-independent
    // -> bitwise deterministic and EXACT (no quantization beyond the per-edge 2^-28).
    for (int ki = wave; ki < nk; ki += 4) {
        int2 kk = klist[ki];
        long long a = (long long)kk.y;
        int cnt = CNT[kk.x];
        const int2* row = CSR + (size_t)kk.x * CAP;
        for (int e = lane; e < cnt; e += 64) {
            int2 ent = row[e];
            unsigned long long prod = (unsigned long long)(a * (long long)ent.y);
            atomicAdd(&acc[ent.x], prod);
        }
    }
    __syncthreads();

    // epilogue: exact int64 -> double -> single fp32 rounding, then threshold
    float* orow = out + (size_t)c * N * N + (size_t)m * N;
    for (int t = threadIdx.x; t < N / 4; t += 256) {
        float4 h;
        float* hp = (float*)&h;
#pragma unroll
        for (int u = 0; u < 4; ++u) {
            double d = (double)(long long)acc[t * 4 + u] * INV_P56;
            float f = (float)d;
            hp[u] = (f > THRESH) ? f : 0.f;
        }
        *(float4*)&orow[t * 4] = h;
    }
}

extern "C" void kernel_launch(void* const* d_in, const int* in_sizes, int n_in,
                              void* d_out, int out_size, void* d_ws, size_t ws_size,
                              hipStream_t stream) {
    const int*   ei = (const int*)d_in[0];     // [5, 2, 131072]
    const float* ev = (const float*)d_in[1];   // [5, 131072]
    const float* w1 = (const float*)d_in[2];   // [2, 5]
    const float* w2 = (const float*)d_in[3];   // [2, 5]
    float* out = (float*)d_out;                // H (2*N*N) then F1(10), F2(10)

    int*  wsI = (int*)d_ws;
    int*  A1d = wsI + A1_OFF;
    int*  A2d = wsI + A2_OFF;
    int*  CNT = wsI + CNT_OFF;
    int2* CSR = (int2*)(wsI + CSR_OFF);
    float* F  = (float*)(wsI + F_OFF);

    float* out_tail = out + (size_t)NCH * N * N;
    softmax_kernel<<<1, 64, 0, stream>>>(w1, w2, F, out_tail);

    int total_edges = NREL * NEDGE;
    for (int c = 0; c < NCH; ++c) {
        // zero dense accumulators + CSR counts (CSR payload governed by CNT)
        hipMemsetAsync(d_ws, 0, (size_t)(2 * (size_t)N * N + N) * sizeof(int), stream);
        scatter_ch<<<(total_edges + 255) / 256, 256, 0, stream>>>(ei, ev, F, A1d, A2d, c);
        csr_build<<<N, 256, 0, stream>>>(A2d, CNT, CSR);
        spgemm<<<N, 256, 0, stream>>>(A1d, CNT, CSR, out, c);
    }
}

// Round 4
// 245.008 us; speedup vs baseline: 10.7571x; 2.3064x over previous
//
#include <hip/hip_runtime.h>
#include <math.h>

#define N 4096
#define NREL 5
#define NCH 2
#define NEDGE 131072
#define THRESH 0.05f
#define FSCALE 268435456.0f          // 2^28 fixed point for adjacency entries (identical to rounds 1/3)
#define INV_P56 (1.0/72057594037927936.0)   // 2^-56 (double, exact)
#define ROWCAP 192                   // per (row, col-half) capacity: Poisson(80), 192 = +12.5 sigma

// Entries per (row, half) region per channel:
#define ROWS2 ((size_t)N * 2 * ROWCAP)

// ws layout in 4-byte elements:
//   CNT  [0, 2N)                      shared row-half counts (both matrices share structure)
//   E2   [E2_OFF ...)                 int2 (local col, q2) per channel, N*2*ROWCAP each
//   A1V  [A1V_OFF ...)                int q1 per channel, parallel ordering to E2
//   F    [F_OFF, F_OFF+20)            softmax weights
#define CNT_OFF  ((size_t)0)
#define E2_OFF   ((size_t)(2 * N))
#define A1V_OFF  (E2_OFF + (size_t)NCH * ROWS2 * 2)
#define F_OFF    (A1V_OFF + (size_t)NCH * ROWS2)

__global__ void softmax_kernel(const float* __restrict__ w1,
                               const float* __restrict__ w2,
                               float* __restrict__ F,
                               float* __restrict__ out_tail) {
    int c = threadIdx.x;
    if (c < 2 * NCH) {
        const float* w = (c < NCH) ? w1 : w2;
        int row = c % NCH;
        int base = (c < NCH) ? 0 : NCH * NREL;
        float m = -1e30f;
        for (int r = 0; r < NREL; ++r) m = fmaxf(m, w[row * NREL + r]);
        float e[NREL];
        float s = 0.f;
        for (int r = 0; r < NREL; ++r) { e[r] = expf(w[row * NREL + r] - m); s += e[r]; }
        float inv = 1.0f / s;
        for (int r = 0; r < NREL; ++r) {
            float f = e[r] * inv;
            F[base + row * NREL + r] = f;
            out_tail[base + row * NREL + r] = f;
        }
    }
}

// Append edges directly to bucketed CSR. Duplicate (i,j) entries are NOT merged:
// integer accumulation in spgemm is distributive, so the result is bit-identical
// to dense coalescing. Entry order is nondeterministic but consumers are
// order-independent integer sums -> deterministic output.
__global__ void scatter_csr(const int* __restrict__ ei,
                            const float* __restrict__ ev,
                            const float* __restrict__ F,
                            int* __restrict__ CNT,
                            int2* __restrict__ E2,
                            int* __restrict__ A1V) {
    int t = blockIdx.x * blockDim.x + threadIdx.x;
    if (t >= NREL * NEDGE) return;
    int r = t / NEDGE;
    int e = t - r * NEDGE;
    int i = ei[(size_t)(r * 2 + 0) * NEDGE + e];
    int j = ei[(size_t)(r * 2 + 1) * NEDGE + e];
    float v = ev[(size_t)r * NEDGE + e];
    int h  = j >> 11;            // column half
    int jl = j & 2047;           // local column
    int pos = atomicAdd(&CNT[i * 2 + h], 1);
    if (pos < ROWCAP) {
        size_t idx = ((size_t)i * 2 + h) * ROWCAP + pos;
        // per-edge quantization identical to the passing round-1/3 kernels
        int q1a = __float2int_rn(F[0 * NREL + r] * v * FSCALE);              // F1 ch0
        int q1b = __float2int_rn(F[1 * NREL + r] * v * FSCALE);              // F1 ch1
        int q2a = __float2int_rn(F[NCH * NREL + 0 * NREL + r] * v * FSCALE); // F2 ch0
        int q2b = __float2int_rn(F[NCH * NREL + 1 * NREL + r] * v * FSCALE); // F2 ch1
        E2[idx]         = make_int2(jl, q2a);
        E2[ROWS2 + idx] = make_int2(jl, q2b);
        A1V[idx]         = q1a;
        A1V[ROWS2 + idx] = q1b;
    }
}

// One block per (output row m, column half h, channel c).
// LDS: 16KB acc + 3KB klist = 19.4KB -> 8 blocks/CU, 32 waves/CU.
__launch_bounds__(256, 8)
__global__ void spgemm(const int* __restrict__ CNT,
                       const int2* __restrict__ E2,
                       const int* __restrict__ A1V,
                       float* __restrict__ out) {
    __shared__ unsigned long long acc[2048];   // exact int64 accumulator, 16KB
    __shared__ int kKC[2 * ROWCAP];            // k | (cnt << 12)
    __shared__ int kA [2 * ROWCAP];            // A1[m][k] raw int
    const int m = blockIdx.x;
    const int h = blockIdx.y;
    const int c = blockIdx.z;
    const int2* __restrict__ e2 = E2  + (size_t)c * ROWS2;
    const int*  __restrict__ a1 = A1V + (size_t)c * ROWS2;

    for (int i = threadIdx.x; i < 2048; i += 256) acc[i] = 0ULL;

    // klist = A1 row m = both buckets (klist needs ALL k, independent of h).
    // Prefetch k, a, and inner-row count in one cooperative pass.
    int nk0 = min(CNT[m * 2 + 0], ROWCAP);
    int nk1 = min(CNT[m * 2 + 1], ROWCAP);
    int nk = nk0 + nk1;
    for (int i = threadIdx.x; i < nk; i += 256) {
        int b  = (i >= nk0) ? 1 : 0;
        int ii = i - (b ? nk0 : 0);
        size_t idx = ((size_t)m * 2 + b) * ROWCAP + ii;
        int k = e2[idx].x + (b << 11);
        int cnt = min(CNT[k * 2 + h], ROWCAP);
        kKC[i] = k | (cnt << 12);
        kA[i]  = a1[idx];
    }
    __syncthreads();

    // 8 independent 32-lane k-streams; product ia*iv fits int64 exactly;
    // u64 LDS atomics are order-independent -> deterministic and exact.
    const int slot   = threadIdx.x >> 5;
    const int lane32 = threadIdx.x & 31;
    for (int ki = slot; ki < nk; ki += 8) {
        int kc  = kKC[ki];
        int k   = kc & 0xFFF;
        int cnt = kc >> 12;
        long long a = (long long)kA[ki];
        const int2* __restrict__ row = e2 + ((size_t)k * 2 + h) * ROWCAP;
        for (int e = lane32; e < cnt; e += 32) {
            int2 ent = row[e];
            atomicAdd(&acc[ent.x], (unsigned long long)(a * (long long)ent.y));
        }
    }
    __syncthreads();

    // epilogue: exact int64 -> double -> single fp32 rounding, threshold, store
    float* orow = out + (size_t)c * N * N + (size_t)m * N + ((size_t)h << 11);
    for (int t = threadIdx.x; t < 2048 / 4; t += 256) {
        float4 hv;
        float* hp = (float*)&hv;
#pragma unroll
        for (int u = 0; u < 4; ++u) {
            double d = (double)(long long)acc[t * 4 + u] * INV_P56;
            float f = (float)d;
            hp[u] = (f > THRESH) ? f : 0.f;
        }
        *(float4*)&orow[t * 4] = hv;
    }
}

extern "C" void kernel_launch(void* const* d_in, const int* in_sizes, int n_in,
                              void* d_out, int out_size, void* d_ws, size_t ws_size,
                              hipStream_t stream) {
    const int*   ei = (const int*)d_in[0];     // [5, 2, 131072]
    const float* ev = (const float*)d_in[1];   // [5, 131072]
    const float* w1 = (const float*)d_in[2];   // [2, 5]
    const float* w2 = (const float*)d_in[3];   // [2, 5]
    float* out = (float*)d_out;                // H (2*N*N) then F1(10), F2(10)

    int*   wsI = (int*)d_ws;
    int*   CNT = wsI + CNT_OFF;
    int2*  E2  = (int2*)(wsI + E2_OFF);
    int*   A1V = wsI + A1V_OFF;
    float* F   = (float*)(wsI + F_OFF);

    float* out_tail = out + (size_t)NCH * N * N;
    softmax_kernel<<<1, 64, 0, stream>>>(w1, w2, F, out_tail);

    // only the counts need zeroing (32KB)
    hipMemsetAsync(CNT, 0, (size_t)2 * N * sizeof(int), stream);

    int total_edges = NREL * NEDGE;
    scatter_csr<<<(total_edges + 255) / 256, 256, 0, stream>>>(ei, ev, F, CNT, E2, A1V);

    spgemm<<<dim3(N, 2, NCH), 256, 0, stream>>>(CNT, E2, A1V, out);
}

// Round 5
// 213.068 us; speedup vs baseline: 12.3696x; 1.1499x over previous
//
#include <hip/hip_runtime.h>
#include <math.h>

#define N 4096
#define NREL 5
#define NCH 2
#define NEDGE 131072
#define THRESH 0.05f
#define FSCALE 268435456.0f          // 2^28 fixed point for adjacency entries
#define INV_P56 (1.0/72057594037927936.0)   // 2^-56 (double, exact)
#define ROWCAP 192                   // per (row, col-half) capacity: Poisson(80), +12.5 sigma

#define ROWS2 ((size_t)N * 2 * ROWCAP)

// ws layout in 4-byte elements:
//   CNT  [0, 2N)        shared row-half counts (A1/A2 share structure)
//   E2   [E2_OFF ...)   int2 (local col, q2) per channel, N*2*ROWCAP each
//   A1V  [A1V_OFF ...)  int q1 per channel, parallel ordering to E2
//   F    [F_OFF, +20)   softmax weights
#define CNT_OFF  ((size_t)0)
#define E2_OFF   ((size_t)(2 * N))
#define A1V_OFF  (E2_OFF + (size_t)NCH * ROWS2 * 2)
#define F_OFF    (A1V_OFF + (size_t)NCH * ROWS2)

__global__ void softmax_kernel(const float* __restrict__ w1,
                               const float* __restrict__ w2,
                               float* __restrict__ F,
                               float* __restrict__ out_tail) {
    int c = threadIdx.x;
    if (c < 2 * NCH) {
        const float* w = (c < NCH) ? w1 : w2;
        int row = c % NCH;
        int base = (c < NCH) ? 0 : NCH * NREL;
        float m = -1e30f;
        for (int r = 0; r < NREL; ++r) m = fmaxf(m, w[row * NREL + r]);
        float e[NREL];
        float s = 0.f;
        for (int r = 0; r < NREL; ++r) { e[r] = expf(w[row * NREL + r] - m); s += e[r]; }
        float inv = 1.0f / s;
        for (int r = 0; r < NREL; ++r) {
            float f = e[r] * inv;
            F[base + row * NREL + r] = f;
            out_tail[base + row * NREL + r] = f;
        }
    }
}

// Append edges directly to bucketed CSR. Duplicates unmerged (distributive int
// accumulation => bit-identical to dense coalescing); entry order racy but all
// consumers are order-independent integer sums -> deterministic output.
__global__ void scatter_csr(const int* __restrict__ ei,
                            const float* __restrict__ ev,
                            const float* __restrict__ F,
                            int* __restrict__ CNT,
                            int2* __restrict__ E2,
                            int* __restrict__ A1V) {
    int t = blockIdx.x * blockDim.x + threadIdx.x;
    if (t >= NREL * NEDGE) return;
    int r = t / NEDGE;
    int e = t - r * NEDGE;
    int i = ei[(size_t)(r * 2 + 0) * NEDGE + e];
    int j = ei[(size_t)(r * 2 + 1) * NEDGE + e];
    float v = ev[(size_t)r * NEDGE + e];
    int h  = j >> 11;
    int jl = j & 2047;
    int pos = atomicAdd(&CNT[i * 2 + h], 1);
    if (pos < ROWCAP) {
        size_t idx = ((size_t)i * 2 + h) * ROWCAP + pos;
        int q1a = __float2int_rn(F[0 * NREL + r] * v * FSCALE);
        int q1b = __float2int_rn(F[1 * NREL + r] * v * FSCALE);
        int q2a = __float2int_rn(F[NCH * NREL + 0 * NREL + r] * v * FSCALE);
        int q2b = __float2int_rn(F[NCH * NREL + 1 * NREL + r] * v * FSCALE);
        E2[idx]          = make_int2(jl, q2a);
        E2[ROWS2 + idx]  = make_int2(jl, q2b);
        A1V[idx]         = q1a;
        A1V[ROWS2 + idx] = q1b;
    }
}

// One block per (output row m, column half h, channel c).
// 8 slots x 32 lanes; each slot runs TWO independent k-streams (ki, ki+8) with
// int4 (2-entry) loads -> 4 independent load->mad64->atomic chains per slot.
__launch_bounds__(256, 8)
__global__ void spgemm(const int* __restrict__ CNT,
                       const int2* __restrict__ E2,
                       const int* __restrict__ A1V,
                       float* __restrict__ out) {
    __shared__ unsigned long long acc[2048];   // exact int64 accumulator, 16KB
    __shared__ int kKC[2 * ROWCAP];            // k | (cnt << 12)
    __shared__ int kA [2 * ROWCAP];            // A1[m][k] raw int
    const int m = blockIdx.x;
    const int h = blockIdx.y;
    const int c = blockIdx.z;
    const int2* __restrict__ e2 = E2  + (size_t)c * ROWS2;
    const int*  __restrict__ a1 = A1V + (size_t)c * ROWS2;

    for (int i = threadIdx.x; i < 2048; i += 256) acc[i] = 0ULL;

    int nk0 = min(CNT[m * 2 + 0], ROWCAP);
    int nk1 = min(CNT[m * 2 + 1], ROWCAP);
    int nk = nk0 + nk1;
    for (int i = threadIdx.x; i < nk; i += 256) {
        int b  = (i >= nk0) ? 1 : 0;
        int ii = i - (b ? nk0 : 0);
        size_t idx = ((size_t)m * 2 + b) * ROWCAP + ii;
        int k = e2[idx].x + (b << 11);
        int cnt = min(CNT[k * 2 + h], ROWCAP);
        kKC[i] = k | (cnt << 12);
        kA[i]  = a1[idx];
    }
    __syncthreads();

    const int slot = threadIdx.x >> 5;
    const int lane = threadIdx.x & 31;
    // Row byte offsets fit 32 bits: (k*2+h)*ROWCAP*8 <= 12.6MB.
    const char* __restrict__ e2base = (const char*)e2;

    for (int ki = slot; ki < nk; ki += 16) {
        int kcA  = kKC[ki];
        int cntA = kcA >> 12;
        long long aA = (long long)kA[ki];
        unsigned offA = (unsigned)(((kcA & 0xFFF) * 2 + h) * (ROWCAP * 8));
        const int4* __restrict__ rowA = (const int4*)(e2base + offA);

        int kiB = ki + 8;
        bool hasB = kiB < nk;
        int kcB  = hasB ? kKC[kiB] : 0;
        int cntB = hasB ? (kcB >> 12) : 0;
        long long aB = hasB ? (long long)kA[kiB] : 0;
        unsigned offB = (unsigned)(((kcB & 0xFFF) * 2 + h) * (ROWCAP * 8));
        const int4* __restrict__ rowB = (const int4*)(e2base + offB);

        int PA = (cntA + 1) >> 1;           // int4 pairs in stream A
        int PB = (cntB + 1) >> 1;
        int P  = (PA > PB) ? PA : PB;
        for (int p = lane; p < P; p += 32) {
            int4 qa, qb;
            bool vA = p < PA, vB = p < PB;
            if (vA) qa = rowA[p];
            if (vB) qb = rowB[p];
            if (vA) {
                atomicAdd(&acc[qa.x], (unsigned long long)(aA * (long long)qa.y));
                if (2 * p + 1 < cntA)
                    atomicAdd(&acc[qa.z], (unsigned long long)(aA * (long long)qa.w));
            }
            if (vB) {
                atomicAdd(&acc[qb.x], (unsigned long long)(aB * (long long)qb.y));
                if (2 * p + 1 < cntB)
                    atomicAdd(&acc[qb.z], (unsigned long long)(aB * (long long)qb.w));
            }
        }
    }
    __syncthreads();

    // epilogue: exact int64 -> double -> single fp32 rounding, threshold, store
    float* orow = out + (size_t)c * N * N + (size_t)m * N + ((size_t)h << 11);
    for (int t = threadIdx.x; t < 2048 / 4; t += 256) {
        float4 hv;
        float* hp = (float*)&hv;
#pragma unroll
        for (int u = 0; u < 4; ++u) {
            double d = (double)(long long)acc[t * 4 + u] * INV_P56;
            float f = (float)d;
            hp[u] = (f > THRESH) ? f : 0.f;
        }
        *(float4*)&orow[t * 4] = hv;
    }
}

extern "C" void kernel_launch(void* const* d_in, const int* in_sizes, int n_in,
                              void* d_out, int out_size, void* d_ws, size_t ws_size,
                              hipStream_t stream) {
    const int*   ei = (const int*)d_in[0];     // [5, 2, 131072]
    const float* ev = (const float*)d_in[1];   // [5, 131072]
    const float* w1 = (const float*)d_in[2];   // [2, 5]
    const float* w2 = (const float*)d_in[3];   // [2, 5]
    float* out = (float*)d_out;                // H (2*N*N) then F1(10), F2(10)

    int*   wsI = (int*)d_ws;
    int*   CNT = wsI + CNT_OFF;
    int2*  E2  = (int2*)(wsI + E2_OFF);
    int*   A1V = wsI + A1V_OFF;
    float* F   = (float*)(wsI + F_OFF);

    float* out_tail = out + (size_t)NCH * N * N;
    softmax_kernel<<<1, 64, 0, stream>>>(w1, w2, F, out_tail);

    hipMemsetAsync(CNT, 0, (size_t)2 * N * sizeof(int), stream);

    int total_edges = NREL * NEDGE;
    scatter_csr<<<(total_edges + 255) / 256, 256, 0, stream>>>(ei, ev, F, CNT, E2, A1V);

    spgemm<<<dim3(N, 2, NCH), 256, 0, stream>>>(CNT, E2, A1V, out);
}